// Round 5
// baseline (505.142 us; speedup 1.0000x reference)
//
#include <hip/hip_runtime.h>
#include <math.h>

// Problem constants (from reference setup_inputs)
constexpr int B = 16, N = 1024, Cin = 64, C = 64, K = 3;
constexpr int BN = B * N;
constexpr int GRID = 512;          // 2 blocks/CU on 256 CUs -> co-resident
#define LN_EPS 1e-5f

// ---------------------------------------------------------------------------
// Device-scope grid barrier (persistent-kernel style). Counters in global ws,
// zeroed by hipMemsetAsync before launch. Bounded spin: on pathological
// non-residency we produce wrong results (test fails) instead of hanging.
// ---------------------------------------------------------------------------
__device__ __forceinline__ void gbar(unsigned int* cnt, unsigned int target) {
    __threadfence();                           // make my block's writes visible device-wide
    __syncthreads();
    if (threadIdx.x == 0) {
        __hip_atomic_fetch_add(cnt, 1u, __ATOMIC_RELEASE, __HIP_MEMORY_SCOPE_AGENT);
        int spins = 0;
        while (__hip_atomic_load(cnt, __ATOMIC_ACQUIRE, __HIP_MEMORY_SCOPE_AGENT) < target) {
            if (++spins > (1 << 20)) break;    // ~0.2s bail-out
        }
    }
    __syncthreads();
    __threadfence();                           // acquire other blocks' writes
}

// ---------------------------------------------------------------------------
// Matvec core: wave computes rows row..row+3 of A[b] @ x (x staged in LDS).
// ---------------------------------------------------------------------------
__device__ __forceinline__ void matvec4(const float* __restrict__ Ab,
                                        const float4* __restrict__ xs,
                                        int row, int lane,
                                        float& a0, float& a1, float& a2, float& a3) {
    const float4* r0 = (const float4*)(Ab + (size_t)(row + 0) * N);
    const float4* r1 = (const float4*)(Ab + (size_t)(row + 1) * N);
    const float4* r2 = (const float4*)(Ab + (size_t)(row + 2) * N);
    const float4* r3 = (const float4*)(Ab + (size_t)(row + 3) * N);
    a0 = a1 = a2 = a3 = 0.f;
    #pragma unroll
    for (int k = 0; k < 4; ++k) {
        int idx = k * 64 + lane;
        float4 xx = xs[idx];
        float4 v0 = r0[idx];
        float4 v1 = r1[idx];
        float4 v2 = r2[idx];
        float4 v3 = r3[idx];
        a0 += v0.x * xx.x + v0.y * xx.y + v0.z * xx.z + v0.w * xx.w;
        a1 += v1.x * xx.x + v1.y * xx.y + v1.z * xx.z + v1.w * xx.w;
        a2 += v2.x * xx.x + v2.y * xx.y + v2.z * xx.z + v2.w * xx.w;
        a3 += v3.x * xx.x + v3.y * xx.y + v3.z * xx.z + v3.w * xx.w;
    }
    #pragma unroll
    for (int off = 32; off; off >>= 1) {
        a0 += __shfl_xor(a0, off);
        a1 += __shfl_xor(a1, off);
        a2 += __shfl_xor(a2, off);
        a3 += __shfl_xor(a3, off);
    }
}

// ---------------------------------------------------------------------------
// One persistent kernel, 512 blocks x 256. Block -> (b = blk/32, 32 rows).
// Phase 0: P0 = X.sum(-1) (all) + ht = h^T (blocks 0..63)      | gbar
// Phase 1: P1 = A @ P0                                          | gbar
// Phase 2: P2 = A @ P1                                          | gbar
// Phase 3: P3 rows in LDS + taps + LayerNorm + tanh -> out
// ---------------------------------------------------------------------------
__global__ void __launch_bounds__(256)
fused_persist(const float* __restrict__ A, const float* __restrict__ X,
              const float* __restrict__ h, const float* __restrict__ gamma,
              const float* __restrict__ beta, float* __restrict__ out,
              unsigned int* __restrict__ bar, float* __restrict__ P,
              float* __restrict__ ht) {
    __shared__ __align__(16) float smem[64 * 65];   // 16.6 KB, aliased per phase
    __shared__ float p3s[32];
    const int tid  = threadIdx.x;
    const int lane = tid & 63;
    const int w    = tid >> 6;
    const int gw   = blockIdx.x * 4 + w;            // 0..2047

    // ---- Phase 0a: P0[p] = sum_c X[p,c], wave per p, lane = c -------------
    for (int p = gw; p < BN; p += 4 * GRID) {       // 8 iterations
        float v = X[(size_t)p * Cin + lane];
        #pragma unroll
        for (int off = 32; off; off >>= 1) v += __shfl_xor(v, off);
        if (lane == 0) P[p] = v;
    }

    // ---- Phase 0b: ht[i][n][c] = h[i][c][n], 64 blocks --------------------
    if (blockIdx.x < (K + 1) * (N / 64)) {
        int i  = blockIdx.x / (N / 64);
        int n0 = (blockIdx.x % (N / 64)) * 64;
        const float* hi = h + (size_t)i * C * N;
        #pragma unroll
        for (int cc = w; cc < 64; cc += 4)
            smem[cc * 65 + lane] = hi[(size_t)cc * N + n0 + lane];    // coalesced along n
        __syncthreads();
        float* hti = ht + (size_t)i * N * C;
        #pragma unroll
        for (int nn = w; nn < 64; nn += 4)
            hti[(size_t)(n0 + nn) * C + lane] = smem[lane * 65 + nn]; // coalesced along c
    }
    gbar(bar + 0, GRID);

    // ---- Phases 1..2: P[it+1] = A @ P[it] ---------------------------------
    const int b     = blockIdx.x >> 5;              // 32 blocks per batch
    const int rbase = (blockIdx.x & 31) << 5;       // 32 rows per block
    const float* Ab = A + ((size_t)b << 20);
    float4* xs = (float4*)smem;                     // 4 KB region

    for (int it = 0; it < 2; ++it) {
        const float* xsrc = P + (size_t)it * BN + (size_t)b * N;
        float* ydst       = P + (size_t)(it + 1) * BN + (size_t)b * N;
        xs[tid] = ((const float4*)xsrc)[tid];
        __syncthreads();
        #pragma unroll
        for (int r = 0; r < 2; ++r) {
            const int row = rbase + r * 16 + w * 4;
            float a0, a1, a2, a3;
            matvec4(Ab, xs, row, lane, a0, a1, a2, a3);
            if (lane == 0) {
                float* yb = ydst + row;
                yb[0] = a0; yb[1] = a1; yb[2] = a2; yb[3] = a3;
            }
        }
        gbar(bar + 1 + it, GRID);                   // also protects xs reuse
    }

    // ---- Phase 3: P3 rows (kept in LDS) + taps + LN + tanh ----------------
    {
        const float* xsrc = P + (size_t)2 * BN + (size_t)b * N;
        xs[tid] = ((const float4*)xsrc)[tid];
        __syncthreads();
        #pragma unroll
        for (int r = 0; r < 2; ++r) {
            const int row = rbase + r * 16 + w * 4;
            float a0, a1, a2, a3;
            matvec4(Ab, xs, row, lane, a0, a1, a2, a3);
            if (lane == 0) {
                int o = r * 16 + w * 4;
                p3s[o + 0] = a0; p3s[o + 1] = a1; p3s[o + 2] = a2; p3s[o + 3] = a3;
            }
        }
        __syncthreads();

        const float g  = gamma[lane];
        const float be = beta[lane];
        #pragma unroll
        for (int j = 0; j < 8; ++j) {               // wave w: 8 of the 32 n's
            const int nn = w * 8 + j;
            const int n  = rbase + nn;
            float y = 0.f;
            #pragma unroll
            for (int i = 0; i < 3; ++i) {
                float hv = ht[((size_t)i * N + n) * C + lane];       // coalesced
                float pv = P[(size_t)i * BN + (size_t)b * N + n];    // broadcast
                y += hv * pv;
            }
            y += ht[((size_t)3 * N + n) * C + lane] * p3s[nn];
            float s = y;
            #pragma unroll
            for (int off = 32; off; off >>= 1) s += __shfl_xor(s, off);
            float mu = s * (1.0f / 64.0f);
            float d  = y - mu;
            float v  = d * d;
            #pragma unroll
            for (int off = 32; off; off >>= 1) v += __shfl_xor(v, off);
            float var = v * (1.0f / 64.0f);
            float yn  = d * rsqrtf(var + LN_EPS) * g + be;
            out[((size_t)b * N + n) * C + lane] = tanhf(yn);
        }
    }
}

// ---------------------------------------------------------------------------
extern "C" void kernel_launch(void* const* d_in, const int* in_sizes, int n_in,
                              void* d_out, int out_size, void* d_ws, size_t ws_size,
                              hipStream_t stream) {
    const float* A     = (const float*)d_in[0];  // [B,N,N]
    const float* X     = (const float*)d_in[1];  // [B,N,Cin]
    const float* h     = (const float*)d_in[2];  // [K+1,C,N]
    const float* gamma = (const float*)d_in[3];  // [C]
    const float* beta  = (const float*)d_in[4];  // [C]
    float* out = (float*)d_out;                  // [B,N,C]

    // ws layout: [0..63] barrier counters (zeroed here; ws is 0xAA-poisoned),
    // then P[3][B][N], then ht[K+1][N][C]
    unsigned int* bar = (unsigned int*)d_ws;
    float* P  = (float*)d_ws + 64;
    float* ht = P + (size_t)3 * BN;

    hipMemsetAsync(bar, 0, 64 * sizeof(unsigned int), stream);  // graph-capturable
    fused_persist<<<GRID, 256, 0, stream>>>(A, X, h, gamma, beta, out, bar, P, ht);
}

// Round 6
// 218.057 us; speedup vs baseline: 2.3166x; 2.3166x over previous
//
#include <hip/hip_runtime.h>
#include <math.h>

// Problem constants (from reference setup_inputs)
constexpr int B = 16, N = 1024, Cin = 64, C = 64, K = 3;
constexpr int BN = B * N;
constexpr int GRID = 512;          // 2 blocks/CU on 256 CUs -> co-resident (proven round 5)
#define LN_EPS 1e-5f

// ---------------------------------------------------------------------------
// Cheap device-scope grid barrier.
//  - __syncthreads() first: every wave's stores drained (vmcnt(0) before
//    s_barrier), so thread-0's RELEASE rmw (one buffer_wbl2) publishes the
//    whole block's writes.
//  - Spin: RELAXED agent loads (no per-probe cache inv) + s_sleep backoff.
//  - No acquire inv: all cross-block data (P*, ht) is write-once-then-read;
//    readers' XCDs first touch those lines after the writer's wbl2, so L3
//    serves fresh data. Skipping inv keeps A hot in per-XCD L2 for passes 2-3.
//  - Bounded spin: fail-wrong instead of hang if residency ever breaks.
// ---------------------------------------------------------------------------
__device__ __forceinline__ void gbar(unsigned int* cnt, unsigned int target) {
    __syncthreads();
    if (threadIdx.x == 0) {
        __hip_atomic_fetch_add(cnt, 1u, __ATOMIC_RELEASE, __HIP_MEMORY_SCOPE_AGENT);
        int spins = 0;
        while (__hip_atomic_load(cnt, __ATOMIC_RELAXED, __HIP_MEMORY_SCOPE_AGENT) < target) {
            __builtin_amdgcn_s_sleep(4);
            if (++spins > (1 << 20)) break;     // ~100ms bail-out, no TDR hang
        }
    }
    __syncthreads();
}

// ---------------------------------------------------------------------------
// Matvec core: wave computes rows row..row+3 of A[b] @ x (x staged in LDS).
// ---------------------------------------------------------------------------
__device__ __forceinline__ void matvec4(const float* __restrict__ Ab,
                                        const float4* __restrict__ xs,
                                        int row, int lane,
                                        float& a0, float& a1, float& a2, float& a3) {
    const float4* r0 = (const float4*)(Ab + (size_t)(row + 0) * N);
    const float4* r1 = (const float4*)(Ab + (size_t)(row + 1) * N);
    const float4* r2 = (const float4*)(Ab + (size_t)(row + 2) * N);
    const float4* r3 = (const float4*)(Ab + (size_t)(row + 3) * N);
    a0 = a1 = a2 = a3 = 0.f;
    #pragma unroll
    for (int k = 0; k < 4; ++k) {
        int idx = k * 64 + lane;
        float4 xx = xs[idx];
        float4 v0 = r0[idx];
        float4 v1 = r1[idx];
        float4 v2 = r2[idx];
        float4 v3 = r3[idx];
        a0 += v0.x * xx.x + v0.y * xx.y + v0.z * xx.z + v0.w * xx.w;
        a1 += v1.x * xx.x + v1.y * xx.y + v1.z * xx.z + v1.w * xx.w;
        a2 += v2.x * xx.x + v2.y * xx.y + v2.z * xx.z + v2.w * xx.w;
        a3 += v3.x * xx.x + v3.y * xx.y + v3.z * xx.z + v3.w * xx.w;
    }
    #pragma unroll
    for (int off = 32; off; off >>= 1) {
        a0 += __shfl_xor(a0, off);
        a1 += __shfl_xor(a1, off);
        a2 += __shfl_xor(a2, off);
        a3 += __shfl_xor(a3, off);
    }
}

// ---------------------------------------------------------------------------
// One persistent kernel, 512 blocks x 256. Block -> (b = blk/32, 32 rows).
// Phase 0: P0 = X.sum(-1) (all) + ht = h^T (blocks 0..63)      | gbar
// Phase 1: P1 = A @ P0                                          | gbar
// Phase 2: P2 = A @ P1                                          | gbar
// Phase 3: P3 rows in LDS + taps + LayerNorm + tanh
// ---------------------------------------------------------------------------
__global__ void __launch_bounds__(256)
fused_persist(const float* __restrict__ A, const float* __restrict__ X,
              const float* __restrict__ h, const float* __restrict__ gamma,
              const float* __restrict__ beta, float* __restrict__ out,
              unsigned int* __restrict__ bar, float* __restrict__ P,
              float* __restrict__ ht) {
    __shared__ __align__(16) float smem[64 * 65];   // 16.6 KB, aliased per phase
    __shared__ float p3s[32];
    const int tid  = threadIdx.x;
    const int lane = tid & 63;
    const int w    = tid >> 6;
    const int gw   = blockIdx.x * 4 + w;            // 0..2047

    // ---- Phase 0a: P0[p] = sum_c X[p,c], wave per p, lane = c -------------
    for (int p = gw; p < BN; p += 4 * GRID) {       // 8 iterations
        float v = X[(size_t)p * Cin + lane];
        #pragma unroll
        for (int off = 32; off; off >>= 1) v += __shfl_xor(v, off);
        if (lane == 0) P[p] = v;
    }

    // ---- Phase 0b: ht[i][n][c] = h[i][c][n], 64 blocks --------------------
    if (blockIdx.x < (K + 1) * (N / 64)) {
        int i  = blockIdx.x / (N / 64);
        int n0 = (blockIdx.x % (N / 64)) * 64;
        const float* hi = h + (size_t)i * C * N;
        #pragma unroll
        for (int cc = w; cc < 64; cc += 4)
            smem[cc * 65 + lane] = hi[(size_t)cc * N + n0 + lane];    // coalesced along n
        __syncthreads();
        float* hti = ht + (size_t)i * N * C;
        #pragma unroll
        for (int nn = w; nn < 64; nn += 4)
            hti[(size_t)(n0 + nn) * C + lane] = smem[lane * 65 + nn]; // coalesced along c
    }
    gbar(bar + 0, GRID);

    // ---- Phases 1..2: P[it+1] = A @ P[it] ---------------------------------
    const int b     = blockIdx.x >> 5;              // 32 blocks per batch
    const int rbase = (blockIdx.x & 31) << 5;       // 32 rows per block
    const float* Ab = A + ((size_t)b << 20);
    float4* xs = (float4*)smem;                     // 4 KB region

    for (int it = 0; it < 2; ++it) {
        const float* xsrc = P + (size_t)it * BN + (size_t)b * N;
        float* ydst       = P + (size_t)(it + 1) * BN + (size_t)b * N;
        xs[tid] = ((const float4*)xsrc)[tid];
        __syncthreads();
        #pragma unroll
        for (int r = 0; r < 2; ++r) {
            const int row = rbase + r * 16 + w * 4;
            float a0, a1, a2, a3;
            matvec4(Ab, xs, row, lane, a0, a1, a2, a3);
            if (lane == 0) {
                float* yb = ydst + row;
                yb[0] = a0; yb[1] = a1; yb[2] = a2; yb[3] = a3;
            }
        }
        gbar(bar + 1 + it, GRID);                   // also protects xs reuse
    }

    // ---- Phase 3: P3 rows (kept in LDS) + taps + LN + tanh ----------------
    {
        const float* xsrc = P + (size_t)2 * BN + (size_t)b * N;
        xs[tid] = ((const float4*)xsrc)[tid];
        __syncthreads();
        #pragma unroll
        for (int r = 0; r < 2; ++r) {
            const int row = rbase + r * 16 + w * 4;
            float a0, a1, a2, a3;
            matvec4(Ab, xs, row, lane, a0, a1, a2, a3);
            if (lane == 0) {
                int o = r * 16 + w * 4;
                p3s[o + 0] = a0; p3s[o + 1] = a1; p3s[o + 2] = a2; p3s[o + 3] = a3;
            }
        }
        __syncthreads();

        const float g  = gamma[lane];
        const float be = beta[lane];
        #pragma unroll
        for (int j = 0; j < 8; ++j) {               // wave w: 8 of the 32 n's
            const int nn = w * 8 + j;
            const int n  = rbase + nn;
            float y = 0.f;
            #pragma unroll
            for (int i = 0; i < 3; ++i) {
                float hv = ht[((size_t)i * N + n) * C + lane];       // coalesced
                float pv = P[(size_t)i * BN + (size_t)b * N + n];    // broadcast
                y += hv * pv;
            }
            y += ht[((size_t)3 * N + n) * C + lane] * p3s[nn];
            float s = y;
            #pragma unroll
            for (int off = 32; off; off >>= 1) s += __shfl_xor(s, off);
            float mu = s * (1.0f / 64.0f);
            float d  = y - mu;
            float v  = d * d;
            #pragma unroll
            for (int off = 32; off; off >>= 1) v += __shfl_xor(v, off);
            float var = v * (1.0f / 64.0f);
            float yn  = d * rsqrtf(var + LN_EPS) * g + be;
            out[((size_t)b * N + n) * C + lane] = tanhf(yn);
        }
    }
}

// ---------------------------------------------------------------------------
extern "C" void kernel_launch(void* const* d_in, const int* in_sizes, int n_in,
                              void* d_out, int out_size, void* d_ws, size_t ws_size,
                              hipStream_t stream) {
    const float* A     = (const float*)d_in[0];  // [B,N,N]
    const float* X     = (const float*)d_in[1];  // [B,N,Cin]
    const float* h     = (const float*)d_in[2];  // [K+1,C,N]
    const float* gamma = (const float*)d_in[3];  // [C]
    const float* beta  = (const float*)d_in[4];  // [C]
    float* out = (float*)d_out;                  // [B,N,C]

    // ws layout: [0..63] barrier counters (zeroed here; ws is 0xAA-poisoned),
    // then P[3][B][N], then ht[K+1][N][C]
    unsigned int* bar = (unsigned int*)d_ws;
    float* P  = (float*)d_ws + 64;
    float* ht = P + (size_t)3 * BN;

    hipMemsetAsync(bar, 0, 64 * sizeof(unsigned int), stream);  // graph-capturable
    fused_persist<<<GRID, 256, 0, stream>>>(A, X, h, gamma, beta, out, bar, P, ht);
}

// Round 7
// 121.076 us; speedup vs baseline: 4.1721x; 1.8010x over previous
//
#include <hip/hip_runtime.h>
#include <math.h>

// Problem constants (from reference setup_inputs)
constexpr int B = 16, N = 1024, Cin = 64, C = 64, K = 3;
constexpr int BN = B * N;
constexpr int GRID = 512;          // 32 blocks per batch, co-resident (proven r5/r6)
constexpr int ROWS = 32;           // n-rows per block
#define LN_EPS 1e-5f

// ---------------------------------------------------------------------------
// Per-batch barrier (32 blocks) on a private 128B line.
//  - __syncthreads() first: compiler drains vmcnt(0) in every wave before
//    s_barrier, so all agent-scope (sc1, write-through) atomic stores issued
//    by this block are globally visible at the coherence point.
//  - RELAXED add + RELAXED spin: no buffer_wbl2 / buffer_inv cache ops at all.
//  - Bounded spin: fail-wrong instead of hang if co-residency ever breaks.
// ---------------------------------------------------------------------------
__device__ __forceinline__ void bbar(unsigned int* cnt) {
    __syncthreads();
    if (threadIdx.x == 0) {
        __hip_atomic_fetch_add(cnt, 1u, __ATOMIC_RELAXED, __HIP_MEMORY_SCOPE_AGENT);
        int spins = 0;
        while (__hip_atomic_load(cnt, __ATOMIC_RELAXED, __HIP_MEMORY_SCOPE_AGENT) < 32u) {
            __builtin_amdgcn_s_sleep(8);                 // ~0.2 us backoff
            if (++spins > (1 << 17)) break;              // bail, no hang
        }
    }
    __syncthreads();
}

// ---------------------------------------------------------------------------
// Matvec core: wave computes rows row..row+3 of A[b] @ x (x staged in LDS).
// ---------------------------------------------------------------------------
__device__ __forceinline__ void matvec4(const float* __restrict__ Ab,
                                        const float4* __restrict__ xs,
                                        int row, int lane,
                                        float& a0, float& a1, float& a2, float& a3) {
    const float4* r0 = (const float4*)(Ab + (size_t)(row + 0) * N);
    const float4* r1 = (const float4*)(Ab + (size_t)(row + 1) * N);
    const float4* r2 = (const float4*)(Ab + (size_t)(row + 2) * N);
    const float4* r3 = (const float4*)(Ab + (size_t)(row + 3) * N);
    a0 = a1 = a2 = a3 = 0.f;
    #pragma unroll
    for (int k = 0; k < 4; ++k) {
        int idx = k * 64 + lane;
        float4 xx = xs[idx];
        float4 v0 = r0[idx];
        float4 v1 = r1[idx];
        float4 v2 = r2[idx];
        float4 v3 = r3[idx];
        a0 += v0.x * xx.x + v0.y * xx.y + v0.z * xx.z + v0.w * xx.w;
        a1 += v1.x * xx.x + v1.y * xx.y + v1.z * xx.z + v1.w * xx.w;
        a2 += v2.x * xx.x + v2.y * xx.y + v2.z * xx.z + v2.w * xx.w;
        a3 += v3.x * xx.x + v3.y * xx.y + v3.z * xx.z + v3.w * xx.w;
    }
    #pragma unroll
    for (int off = 32; off; off >>= 1) {
        a0 += __shfl_xor(a0, off);
        a1 += __shfl_xor(a1, off);
        a2 += __shfl_xor(a2, off);
        a3 += __shfl_xor(a3, off);
    }
}

// ---------------------------------------------------------------------------
// Persistent kernel, 512 blocks x 256. Block (b = blk/32, rbase = (blk%32)*32)
// owns 32 n-rows of batch b. Batches are fully independent pipelines:
//  Phase 0: P0[b][rbase..+32] = X.sum(-1)  +  hl = h^T slice into LDS | bbar
//  Phase 1: P1 rows = A[b] @ P0[b]                                    | bbar
//  Phase 2: P2 rows = A[b] @ P1[b]                                    | bbar
//  Phase 3: P3 rows (LDS only) + taps + LayerNorm + tanh -> out
// Cross-block P writes are relaxed agent atomics (write-through); all P reads
// happen strictly after the corresponding barrier, so plain loads are fresh.
// ---------------------------------------------------------------------------
__global__ void __launch_bounds__(256)
fused_persist(const float* __restrict__ A, const float* __restrict__ X,
              const float* __restrict__ h, const float* __restrict__ gamma,
              const float* __restrict__ beta, float* __restrict__ out,
              unsigned int* __restrict__ bar, float* __restrict__ P) {
    __shared__ float hl[K + 1][ROWS][C];            // 32 KB: hl[i][nn][c] = h[i][c][rbase+nn]
    __shared__ __align__(16) float4 xs[N / 4];      // 4 KB: current x-vector
    __shared__ float p3s[ROWS];
    const int tid   = threadIdx.x;
    const int lane  = tid & 63;
    const int w     = tid >> 6;                     // wave 0..3
    const int b     = blockIdx.x >> 5;              // batch
    const int rbase = (blockIdx.x & 31) * ROWS;     // this block's rows
    unsigned int* mybar = bar + (size_t)b * 3 * 32; // 3 private lines per batch

    // ---- Phase 0a: P0 for our rows (wave w: 8 n's, lane = c) --------------
    {
        const float* Xb = X + ((size_t)b * N + rbase) * Cin;
        float* P0 = P + (size_t)b * N;
        #pragma unroll
        for (int j = 0; j < 8; ++j) {
            int nn = w * 8 + j;
            float v = Xb[(size_t)nn * Cin + lane];
            #pragma unroll
            for (int off = 32; off; off >>= 1) v += __shfl_xor(v, off);
            if (lane == 0)
                __hip_atomic_store(&P0[rbase + nn], v, __ATOMIC_RELAXED,
                                   __HIP_MEMORY_SCOPE_AGENT);
        }
    }

    // ---- Phase 0b: hl[i][nn][c] = h[i][c][rbase+nn] (thread = (i,c)) ------
    {
        const float* src = h + ((size_t)w * C + lane) * N + rbase;  // i = w, c = lane
        #pragma unroll
        for (int j4 = 0; j4 < 8; ++j4) {
            float4 v = ((const float4*)src)[j4];
            hl[w][j4 * 4 + 0][lane] = v.x;
            hl[w][j4 * 4 + 1][lane] = v.y;
            hl[w][j4 * 4 + 2][lane] = v.z;
            hl[w][j4 * 4 + 3][lane] = v.w;
        }
    }
    bbar(mybar);                                    // P0[b] complete

    // ---- Phases 1..3: matvec chain ---------------------------------------
    const float* Ab = A + ((size_t)b << 20);
    for (int it = 0; it < 3; ++it) {
        const float* xsrc = P + (size_t)it * BN + (size_t)b * N;
        xs[tid] = ((const float4*)xsrc)[tid];       // fresh: first touch after bbar
        __syncthreads();
        float* ydst = P + (size_t)(it + 1) * BN + (size_t)b * N;  // unused when it==2
        #pragma unroll
        for (int r = 0; r < 2; ++r) {
            const int row = rbase + r * 16 + w * 4;
            float a0, a1, a2, a3;
            matvec4(Ab, xs, row, lane, a0, a1, a2, a3);
            if (lane == 0) {
                if (it < 2) {
                    __hip_atomic_store(&ydst[row + 0], a0, __ATOMIC_RELAXED, __HIP_MEMORY_SCOPE_AGENT);
                    __hip_atomic_store(&ydst[row + 1], a1, __ATOMIC_RELAXED, __HIP_MEMORY_SCOPE_AGENT);
                    __hip_atomic_store(&ydst[row + 2], a2, __ATOMIC_RELAXED, __HIP_MEMORY_SCOPE_AGENT);
                    __hip_atomic_store(&ydst[row + 3], a3, __ATOMIC_RELAXED, __HIP_MEMORY_SCOPE_AGENT);
                } else {                            // P3 stays in LDS
                    int o = r * 16 + w * 4;
                    p3s[o + 0] = a0; p3s[o + 1] = a1; p3s[o + 2] = a2; p3s[o + 3] = a3;
                }
            }
        }
        if (it < 2) bbar(mybar + (1 + it) * 32);    // publish P[it+1][b]
        else        __syncthreads();                // publish p3s block-locally
    }

    // ---- Phase 4: taps + LayerNorm + tanh (wave w: 8 n's, lane = c) -------
    const float g  = gamma[lane];
    const float be = beta[lane];
    #pragma unroll
    for (int j = 0; j < 8; ++j) {
        const int nn = w * 8 + j;
        const int n  = rbase + nn;
        float y = p3s[nn] * hl[3][nn][lane];
        #pragma unroll
        for (int i = 0; i < 3; ++i) {
            float pv = P[(size_t)i * BN + (size_t)b * N + n];   // wave-uniform, cached
            y += pv * hl[i][nn][lane];
        }
        float s = y;
        #pragma unroll
        for (int off = 32; off; off >>= 1) s += __shfl_xor(s, off);
        float mu = s * (1.0f / 64.0f);
        float d  = y - mu;
        float v  = d * d;
        #pragma unroll
        for (int off = 32; off; off >>= 1) v += __shfl_xor(v, off);
        float var = v * (1.0f / 64.0f);
        float yn  = d * rsqrtf(var + LN_EPS) * g + be;
        out[((size_t)b * N + n) * C + lane] = tanhf(yn);
    }
}

// ---------------------------------------------------------------------------
extern "C" void kernel_launch(void* const* d_in, const int* in_sizes, int n_in,
                              void* d_out, int out_size, void* d_ws, size_t ws_size,
                              hipStream_t stream) {
    const float* A     = (const float*)d_in[0];  // [B,N,N]
    const float* X     = (const float*)d_in[1];  // [B,N,Cin]
    const float* h     = (const float*)d_in[2];  // [K+1,C,N]
    const float* gamma = (const float*)d_in[3];  // [C]
    const float* beta  = (const float*)d_in[4];  // [C]
    float* out = (float*)d_out;                  // [B,N,C]

    // ws layout: barrier counters (16 batches x 3 x 32 uints = 6 KB, zeroed
    // here; ws arrives 0xAA-poisoned), then P[3][B][N] (192 KB).
    unsigned int* bar = (unsigned int*)d_ws;
    float* P = (float*)((char*)d_ws + 8192);

    hipMemsetAsync(bar, 0, B * 3 * 32 * sizeof(unsigned int), stream);
    fused_persist<<<GRID, 256, 0, stream>>>(A, X, h, gamma, beta, out, bar, P);
}